// Round 1
// baseline (76.458 us; speedup 1.0000x reference)
//
#include <hip/hip_runtime.h>
#include <hip/hip_bf16.h>
#include <math.h>

#define N_    1536
#define HID_  64
#define DX_   192
#define JW_   16
#define JCH_  (N_ / JW_)   /* 96 j-chunks */
#define IB_   (N_ / 64)    /* 24 i-blocks of 64 rows */

// ---------------------------------------------------------------------------
// Kernel 1: A[i][h] = sum_k y[i,k]*W1[h,192+k] + b1[h]   (i = 0..N-1)
//           B[j][h] = sum_k x[j,k]*W1[h,k]
//           c[i] = sum_h (W2[h]/2)*A[i][h] + b2          d[j] = sum_h (W2[h]/2)*B[j][h]
//           wp[h] = W2[h]/2
// block = 256 threads = 4 rows x 64 h; grid = 2N/4 rows.
// ---------------------------------------------------------------------------
__global__ __launch_bounds__(256) void k1(
    const float* __restrict__ x, const float* __restrict__ y,
    const float* __restrict__ W1, const float* __restrict__ b1,
    const float* __restrict__ W2, const float* __restrict__ b2,
    float* __restrict__ Am, float* __restrict__ Bm,
    float* __restrict__ cv, float* __restrict__ dv, float* __restrict__ wp)
{
    int tid = threadIdx.x;
    int r   = blockIdx.x * 4 + (tid >> 6);
    int h   = tid & 63;
    bool aside = (r < N_);
    int row = aside ? r : (r - N_);
    const float4* in4 = (const float4*)((aside ? y : x) + row * DX_);
    const float4* w4  = (const float4*)(W1 + h * (2 * DX_) + (aside ? DX_ : 0));
    float acc = 0.f;
    #pragma unroll
    for (int q = 0; q < DX_ / 4; ++q) {
        float4 iv = in4[q];
        float4 wv = w4[q];
        acc = fmaf(iv.x, wv.x, acc);
        acc = fmaf(iv.y, wv.y, acc);
        acc = fmaf(iv.z, wv.z, acc);
        acc = fmaf(iv.w, wv.w, acc);
    }
    if (aside) acc += b1[h];
    (aside ? Am : Bm)[row * HID_ + h] = acc;

    float wph = 0.5f * W2[h];
    if (blockIdx.x == 0 && tid < 64) wp[h] = wph;

    float v = wph * acc;
    #pragma unroll
    for (int m = 32; m; m >>= 1) v += __shfl_xor(v, m, 64);
    if (h == 0) {
        if (aside) cv[row] = v + b2[0];
        else       dv[row] = v;
    }
}

// ---------------------------------------------------------------------------
// Kernel 2: per wave: 64 rows i (lane <-> i), one chunk of JW_ columns j.
//   z[i,j] = c_i + d_j + sum_h wp[h]*|a_i[h] + b_j[h]|     (== pre-softplus)
//   partial[jc][i] = sum_{j in chunk} exp(z)               (exp(softplus)=1+e^z)
//   t0[i] = softplus(z[i,i])  (written by the unique wave where chunk holds j==i)
// ---------------------------------------------------------------------------
__global__ __launch_bounds__(64) void k2(
    const float* __restrict__ Am, const float* __restrict__ Bm,
    const float* __restrict__ wp, const float* __restrict__ cv,
    const float* __restrict__ dv,
    float* __restrict__ part, float* __restrict__ t0)
{
    int wid = blockIdx.x;
    int ib  = wid % IB_;
    int jc  = wid / IB_;
    int i   = ib * 64 + threadIdx.x;

    float a[HID_];
    #pragma unroll
    for (int q = 0; q < HID_ / 4; ++q)
        ((float4*)a)[q] = ((const float4*)(Am + i * HID_))[q];

    float wv[HID_];
    #pragma unroll
    for (int q = 0; q < HID_ / 4; ++q)
        ((float4*)wv)[q] = ((const float4*)wp)[q];

    float ci = cv[i];
    float se = 0.f;

    for (int jj = 0; jj < JW_; ++jj) {
        int j = jc * JW_ + jj;
        float p = ci + dv[j];
        const float4* Br = (const float4*)(Bm + j * HID_);
        #pragma unroll
        for (int q = 0; q < HID_ / 4; ++q) {
            float4 t = Br[q];   // wave-uniform address -> scalar loads
            p = fmaf(wv[4*q+0], fabsf(a[4*q+0] + t.x), p);
            p = fmaf(wv[4*q+1], fabsf(a[4*q+1] + t.y), p);
            p = fmaf(wv[4*q+2], fabsf(a[4*q+2] + t.z), p);
            p = fmaf(wv[4*q+3], fabsf(a[4*q+3] + t.w), p);
        }
        se += expf(p);
        if (j == i) {
            // softplus(p), stable form; only on the diagonal (rare path)
            t0[i] = fmaxf(p, 0.f) + log1pf(expf(-fabsf(p)));
        }
    }
    part[jc * N_ + i] = se;
}

// ---------------------------------------------------------------------------
// Kernel 3: lse_i = log(N + sum_jc part[jc][i]);  out = mean(lse) - log N - mean(t0)
// single block, double-precision accumulation (final value ~4e-3, tol 7.6e-5).
// ---------------------------------------------------------------------------
__global__ __launch_bounds__(256) void k3(
    const float* __restrict__ part, const float* __restrict__ t0,
    float* __restrict__ out)
{
    __shared__ double red[256];
    int tid = threadIdx.x;
    double acc = 0.0;
    for (int i = tid; i < N_; i += 256) {
        double s = (double)N_;   // the "+1" per j from exp(softplus(z)) = 1 + e^z
        for (int jc = 0; jc < JCH_; ++jc) s += (double)part[jc * N_ + i];
        acc += log(s) - (double)t0[i];
    }
    red[tid] = acc;
    __syncthreads();
    #pragma unroll
    for (int st = 128; st; st >>= 1) {
        if (tid < st) red[tid] += red[tid + st];
        __syncthreads();
    }
    if (tid == 0) out[0] = (float)(red[0] / (double)N_ - log((double)N_));
}

extern "C" void kernel_launch(void* const* d_in, const int* in_sizes, int n_in,
                              void* d_out, int out_size, void* d_ws, size_t ws_size,
                              hipStream_t stream)
{
    const float* x  = (const float*)d_in[0];
    const float* y  = (const float*)d_in[1];
    const float* W1 = (const float*)d_in[2];
    const float* b1 = (const float*)d_in[3];
    const float* W2 = (const float*)d_in[4];
    const float* b2 = (const float*)d_in[5];
    // d_in[6] = mask: unused by the reference.

    float* ws   = (float*)d_ws;
    float* Am   = ws;                    // N*HID
    float* Bm   = Am + N_ * HID_;        // N*HID
    float* cv   = Bm + N_ * HID_;        // N
    float* dv   = cv + N_;               // N
    float* wp   = dv + N_;               // HID
    float* part = wp + HID_;             // JCH_*N
    float* t0   = part + JCH_ * N_;      // N

    hipLaunchKernelGGL(k1, dim3((2 * N_) / 4), dim3(256), 0, stream,
                       x, y, W1, b1, W2, b2, Am, Bm, cv, dv, wp);
    hipLaunchKernelGGL(k2, dim3(IB_ * JCH_), dim3(64), 0, stream,
                       Am, Bm, wp, cv, dv, part, t0);
    hipLaunchKernelGGL(k3, dim3(1), dim3(256), 0, stream, part, t0, (float*)d_out);
}

// Round 2
// 42.292 us; speedup vs baseline: 1.8079x; 1.8079x over previous
//
#include <hip/hip_runtime.h>
#include <hip/hip_bf16.h>
#include <math.h>

#define N_    1536
#define HID_  64
#define DX_   192
#define JW_   16
#define JCH_  (N_ / JW_)   /* 96 j-chunks */
#define IB_   (N_ / 64)    /* 24 i-blocks of 64 rows */

// ---------------------------------------------------------------------------
// Kernel 1: A[i][h] = sum_k y[i,k]*W1[h,192+k] + b1[h]
//           B[j][h] = sum_k x[j,k]*W1[h,k]
//           c[i] = sum_h (W2[h]/2)*A[i][h] + b2 ; d[j] = sum_h (W2[h]/2)*B[j][h]
// 192 blocks x 256 thr. bid<96: A-side (y, W1 second half). else B-side (x).
// W1-half staged TRANSPOSED in LDS as float4[48][64] (lane=h -> conflict-free
// ds_read_b128, and W1 L2 traffic drops from ~150MB to ~9MB).
// ---------------------------------------------------------------------------
__global__ __launch_bounds__(256) void k1(
    const float* __restrict__ x, const float* __restrict__ y,
    const float* __restrict__ W1, const float* __restrict__ b1,
    const float* __restrict__ W2, const float* __restrict__ b2,
    float* __restrict__ Am, float* __restrict__ Bm,
    float* __restrict__ cv, float* __restrict__ dv, float* __restrict__ wp)
{
    __shared__ float4 w1t[48 * 64];   // 48 KiB
    int t = threadIdx.x;
    int h = t & 63;
    int w = t >> 6;                   // wave id 0..3
    bool aSide = (blockIdx.x < 96);

    // stage: thread (h, 12 kq) -> LDS[kq][h]
    const float4* w1row = (const float4*)(W1 + h * (2 * DX_) + (aSide ? DX_ : 0));
    int kq0 = w * 12;
    #pragma unroll
    for (int q = 0; q < 12; ++q)
        w1t[(kq0 + q) * 64 + h] = w1row[kq0 + q];
    __syncthreads();

    int row0 = (blockIdx.x % 96) * 16;
    const float* inp = aSide ? y : x;
    float b1h = aSide ? b1[h] : 0.f;
    float wph = 0.5f * W2[h];
    float b2v = b2[0];

    #pragma unroll
    for (int p = 0; p < 4; ++p) {
        int row = row0 + p * 4 + w;
        const float4* in4 = (const float4*)(inp + row * DX_);
        float acc = b1h;
        #pragma unroll
        for (int q = 0; q < 48; ++q) {
            float4 wv = w1t[q * 64 + h];
            float4 iv = in4[q];
            acc = fmaf(iv.x, wv.x, acc);
            acc = fmaf(iv.y, wv.y, acc);
            acc = fmaf(iv.z, wv.z, acc);
            acc = fmaf(iv.w, wv.w, acc);
        }
        (aSide ? Am : Bm)[row * HID_ + h] = acc;

        float v = wph * acc;
        #pragma unroll
        for (int m = 32; m; m >>= 1) v += __shfl_xor(v, m, 64);
        if (h == 0) {
            if (aSide) cv[row] = v + b2v;
            else       dv[row] = v;
        }
    }
    if (blockIdx.x == 0 && t < 64) wp[t] = 0.5f * W2[t];
}

// ---------------------------------------------------------------------------
// Kernel 2: z[i,j] = c_i + d_j + sum_h wp[h]*|a_i[h] + b_j[h]|
//   part[jc][i] = sum_{j in chunk} exp(z)       (exp(softplus(z)) = 1 + e^z)
//   t0[i] = softplus(z[i,i]) on the diagonal.
// 576 blocks x 256 thr (4 waves); lane <-> i, wave-uniform j chunk of 16.
// Two independent fma chains halve the dependency latency.
// ---------------------------------------------------------------------------
__global__ __launch_bounds__(256) void k2(
    const float* __restrict__ Am, const float* __restrict__ Bm,
    const float* __restrict__ wp, const float* __restrict__ cv,
    const float* __restrict__ dv,
    float* __restrict__ part, float* __restrict__ t0)
{
    int lane = threadIdx.x & 63;
    int sub  = threadIdx.x >> 6;
    int jc   = blockIdx.x % JCH_;
    int ib   = (blockIdx.x / JCH_) * 4 + sub;
    int i    = ib * 64 + lane;

    float a[HID_];
    #pragma unroll
    for (int q = 0; q < HID_ / 4; ++q)
        ((float4*)a)[q] = ((const float4*)(Am + i * HID_))[q];

    float wv[HID_];
    #pragma unroll
    for (int q = 0; q < HID_ / 4; ++q)
        ((float4*)wv)[q] = ((const float4*)wp)[q];

    float ci = cv[i];
    float se = 0.f;

    for (int jj = 0; jj < JW_; ++jj) {
        int j = jc * JW_ + jj;
        float p0 = ci + dv[j];
        float p1 = 0.f;
        const float4* Br = (const float4*)(Bm + j * HID_);
        #pragma unroll
        for (int q = 0; q < HID_ / 4; ++q) {
            float4 t = Br[q];   // wave-uniform address -> scalar path
            p0 = fmaf(wv[4*q+0], fabsf(a[4*q+0] + t.x), p0);
            p1 = fmaf(wv[4*q+1], fabsf(a[4*q+1] + t.y), p1);
            p0 = fmaf(wv[4*q+2], fabsf(a[4*q+2] + t.z), p0);
            p1 = fmaf(wv[4*q+3], fabsf(a[4*q+3] + t.w), p1);
        }
        float p = p0 + p1;
        se += __expf(p);
        if (j == i) {
            t0[i] = fmaxf(p, 0.f) + log1pf(__expf(-fabsf(p)));
        }
    }
    part[jc * N_ + i] = se;
}

// ---------------------------------------------------------------------------
// Kernel 3a: per 64-row block: partial sum of (log(N + sum_jc part) - t0[i]), f64.
// Kernel 3b: combine 24 partials -> out = sum/N - log N.
// ---------------------------------------------------------------------------
__global__ __launch_bounds__(64) void k3a(
    const float* __restrict__ part, const float* __restrict__ t0,
    double* __restrict__ red)
{
    int i = blockIdx.x * 64 + threadIdx.x;
    double s = (double)N_;   // the "+1" per j from exp(softplus(z)) = 1 + e^z
    for (int jc = 0; jc < JCH_; ++jc) s += (double)part[jc * N_ + i];
    double v = log(s) - (double)t0[i];
    #pragma unroll
    for (int m = 32; m; m >>= 1) v += __shfl_xor(v, m, 64);
    if (threadIdx.x == 0) red[blockIdx.x] = v;
}

__global__ __launch_bounds__(64) void k3b(
    const double* __restrict__ red, float* __restrict__ out)
{
    double v = (threadIdx.x < IB_) ? red[threadIdx.x] : 0.0;
    #pragma unroll
    for (int m = 32; m; m >>= 1) v += __shfl_xor(v, m, 64);
    if (threadIdx.x == 0)
        out[0] = (float)(v / (double)N_ - log((double)N_));
}

extern "C" void kernel_launch(void* const* d_in, const int* in_sizes, int n_in,
                              void* d_out, int out_size, void* d_ws, size_t ws_size,
                              hipStream_t stream)
{
    const float* x  = (const float*)d_in[0];
    const float* y  = (const float*)d_in[1];
    const float* W1 = (const float*)d_in[2];
    const float* b1 = (const float*)d_in[3];
    const float* W2 = (const float*)d_in[4];
    const float* b2 = (const float*)d_in[5];
    // d_in[6] = mask: all-ones, unused by the reference math.

    double* red = (double*)d_ws;          // 24 doubles (first, for alignment)
    float* ws   = (float*)d_ws + 64;      // floats after 256B
    float* Am   = ws;                     // N*HID
    float* Bm   = Am + N_ * HID_;         // N*HID
    float* cv   = Bm + N_ * HID_;         // N
    float* dv   = cv + N_;                // N
    float* wp   = dv + N_;                // HID
    float* part = wp + HID_;              // JCH_*N
    float* t0   = part + JCH_ * N_;       // N

    hipLaunchKernelGGL(k1, dim3(192), dim3(256), 0, stream,
                       x, y, W1, b1, W2, b2, Am, Bm, cv, dv, wp);
    hipLaunchKernelGGL(k2, dim3((IB_ / 4) * JCH_), dim3(256), 0, stream,
                       Am, Bm, wp, cv, dv, part, t0);
    hipLaunchKernelGGL(k3a, dim3(IB_), dim3(64), 0, stream, part, t0, red);
    hipLaunchKernelGGL(k3b, dim3(1), dim3(64), 0, stream, red, (float*)d_out);
}